// Round 14
// baseline (21.017 us; speedup 1.0000x reference)
//
#include <hip/hip_runtime.h>

// out[b,c,y,x] = (1/50)*albedo * sum_m relu(n.l_m)*env*sin(phi_i)
// Antipodal pairing (i,j)<->(16-i,(j+16)&31):
//   light = n.W + sum_{256 slots} |n.l_s| * hs_s  (invalid slots hs=0;
//   0.5/50 folded into hs and W).  Factorized dot:
//   d(i,j) = sp_i*(nx*st_j - nz*ct_j) + ny*cp_i;  ct_j = STc[(j+8)&31].
// MFMA: O^T(3 x 16pix) += H^T(3 x 256) * P(256 x 16), 8x 16x16x32_f16;
// P in packed fp16 (v_pk_fma_f16 RNE, abs via 0x7FFF mask) = MFMA B operand.
// R14: OCCUPANCY. dur_us ~= kernel time (R1/R2 cross-check), and R13 ran
// 2 waves/SIMD (512 blocks) -- dependent-issue latency exposed (~4x VALU
// inflation at 2 w/SIMD, R2 calib). Fix: table built once in a setup kernel
// (d_ws); main blocks are cheap (8KB hf->LDS copy), GROUPS=4, grid 2048
// blocks, Hf in LDS not VGPRs, launch_bounds(256,8) targets <=64 VGPR =
// 8 waves/SIMD; MFMA chain split into acc0/acc1.

constexpr int HW     = 512 * 512;
constexpr int WAVES  = 4;
constexpr int GROUPS = 4;     // 64 px per wave, 256 px per block

typedef _Float16 half2v __attribute__((ext_vector_type(2)));
typedef _Float16 half8  __attribute__((ext_vector_type(8)));
typedef float    f32x4  __attribute__((ext_vector_type(4)));

// sin/cos((e+1)*pi/16), e = 0..7  (i = e+1)
__device__ constexpr float SPc[8] = {
    0.195090322f, 0.382683432f, 0.555570233f, 0.707106781f,
    0.831469612f, 0.923879533f, 0.980785280f, 1.0f };
__device__ constexpr float CPc[8] = {
    0.980785280f, 0.923879533f, 0.831469612f, 0.707106781f,
    0.555570233f, 0.382683432f, 0.195090322f, 0.0f };
// sin(j*pi/16), j = 0..31  (cos(j*pi/16) = STc[(j+8)&31])
__device__ constexpr float STc[32] = {
    0.0f,          0.195090322f,  0.382683432f,  0.555570233f,
    0.707106781f,  0.831469612f,  0.923879533f,  0.980785280f,
    1.0f,          0.980785280f,  0.923879533f,  0.831469612f,
    0.707106781f,  0.555570233f,  0.382683432f,  0.195090322f,
    0.0f,         -0.195090322f, -0.382683432f, -0.555570233f,
   -0.707106781f, -0.831469612f, -0.923879533f, -0.980785280f,
   -1.0f,         -0.980785280f, -0.923879533f, -0.831469612f,
   -0.707106781f, -0.555570233f, -0.382683432f, -0.195090322f };

union h8u { unsigned u[4]; half8 v; half2v h2[4]; };

// ---------- setup: H^T fragments + W -> d_ws (grid = B) ----------
__global__ __launch_bounds__(256)
void setup_kernel(const float* __restrict__ env,
                  half8* __restrict__ hf_g,     // [B][512]
                  float* __restrict__ Wout)     // [B][9]
{
    __shared__ float lds_env[1536];
    __shared__ float Wred[4][9];
    const int b = blockIdx.x, t = threadIdx.x;
    const int lane = t & 63, wave = t >> 6;

    #pragma unroll
    for (int q = 0; q < 6; ++q)
        lds_env[t + q * 256] = env[(size_t)b * 1536 + t + q * 256];
    __syncthreads();

    #pragma unroll
    for (int ss = 0; ss < 2; ++ss) {
        const int s = t + ss * 256;
        const int tile = s >> 6, ln = s & 63;
        const int kc = ln >> 4, chh = ln & 15;    // k-chunk / channel
        const int j  = tile * 4 + kc;
        half8 f;
        #pragma unroll
        for (int e = 0; e < 8; ++e) {
            const int i = e + 1;
            float v = 0.f;
            if (chh < 3 && !(i == 8 && j >= 16)) {
                const int i2 = 16 - i, j2 = (j + 16) & 31;
                v = (lds_env[(i * 32 + j) * 3 + chh] +
                     lds_env[(i2 * 32 + j2) * 3 + chh]) * (SPc[e] * 0.01f);
            }
            f[e] = (_Float16)v;                   // RNE
        }
        hf_g[b * 512 + s] = f;
    }

    float W[9];
    #pragma unroll
    for (int q = 0; q < 9; ++q) W[q] = 0.0f;
    if (t < 240) {
        int i, j;
        if (t < 224) { i = 1 + (t >> 5); j = t & 31; }
        else         { i = 8;            j = t - 224; }
        const int i2 = 16 - i, j2 = (j + 16) & 31;
        const float sp = SPc[i - 1], cp = CPc[i - 1];
        const float st = STc[j], ct = STc[(j + 8) & 31];
        const float dx = st * sp, dy = cp, dz = -ct * sp;   // |l| = 1
        const float scale = sp * 0.01f;
        const float* ea = lds_env + (i * 32 + j) * 3;
        const float* eb = lds_env + (i2 * 32 + j2) * 3;
        const float hd0 = (ea[0] - eb[0]) * scale;
        const float hd1 = (ea[1] - eb[1]) * scale;
        const float hd2 = (ea[2] - eb[2]) * scale;
        W[0] = dx * hd0; W[1] = dx * hd1; W[2] = dx * hd2;
        W[3] = dy * hd0; W[4] = dy * hd1; W[5] = dy * hd2;
        W[6] = dz * hd0; W[7] = dz * hd1; W[8] = dz * hd2;
    }
    #pragma unroll
    for (int q = 0; q < 9; ++q) {
        float v = W[q];
        #pragma unroll
        for (int off = 32; off > 0; off >>= 1) v += __shfl_down(v, off);
        if (lane == 0) Wred[wave][q] = v;
    }
    __syncthreads();
    if (t < 9) Wout[b * 9 + t] = Wred[0][t] + Wred[1][t] + Wred[2][t] + Wred[3][t];
}

// ---------- main: grid (1024, B), 8 blocks/CU target ----------
__global__ __launch_bounds__(256, 8)
void env_render_main(const float* __restrict__ normal,
                     const float* __restrict__ albedo,
                     const half8* __restrict__ hf_g,
                     const float* __restrict__ Wm,
                     float* __restrict__ out)
{
    __shared__ half8 lds_hf[512];                 // 8 KB
    __shared__ float lds_nrm[WAVES][192];         // 3 KB
    __shared__ float lds_light[WAVES][192];       // 3 KB

    const int b    = blockIdx.y;
    const int t    = threadIdx.x;
    const int lane = t & 63, wave = t >> 6;
    const int ch   = lane & 15, cg = lane >> 4;

    // stage hf -> LDS (coalesced, 32 B/thread)
    {
        const f32x4* src = (const f32x4*)(hf_g + (size_t)b * 512);
        f32x4* dst = (f32x4*)lds_hf;
        dst[t]       = src[t];
        dst[t + 256] = src[t + 256];
    }

    const int wavepx0 = (blockIdx.x * WAVES + wave) * (GROUPS * 16);
    {   // stage this wave's 192 contiguous normal floats
        const float* nsrc = normal + ((size_t)b * HW + wavepx0) * 3;
        #pragma unroll
        for (int q = 0; q < 3; ++q)
            lds_nrm[wave][q * 64 + lane] = nsrc[q * 64 + lane];
    }

    float Wl[9];
    #pragma unroll
    for (int q = 0; q < 9; ++q) Wl[q] = Wm[b * 9 + q];   // uniform -> s_load

    half2v st2[4], ct2[4], sp2[4], cp2[4];
    #pragma unroll
    for (int p = 0; p < 4; ++p) {
        const int ja = (2 * p) * 4 + cg, jb = (2 * p + 1) * 4 + cg;
        st2[p] = half2v{(_Float16)STc[ja], (_Float16)STc[jb]};
        ct2[p] = half2v{(_Float16)STc[(ja + 8) & 31], (_Float16)STc[(jb + 8) & 31]};
        sp2[p] = half2v{(_Float16)SPc[2 * p], (_Float16)SPc[2 * p + 1]};
        cp2[p] = half2v{(_Float16)CPc[2 * p], (_Float16)CPc[2 * p + 1]};
    }
    __syncthreads();   // lds_hf shared across waves; nrm is same-wave

    #pragma unroll
    for (int g = 0; g < GROUPS; ++g) {
        const int pxl = g * 16 + ch;                  // 0..63
        const float n0 = lds_nrm[wave][pxl * 3 + 0];  // conflict-free, cg-bcast
        const float n1 = lds_nrm[wave][pxl * 3 + 1];
        const float n2 = lds_nrm[wave][pxl * 3 + 2];
        const float nx = fmaf(n2, 2.0f, -1.0f);       // flip + decode
        const float ny = fmaf(n1, 2.0f, -1.0f);
        const float nz = fmaf(n0, 2.0f, -1.0f);

        const _Float16 nxh = (_Float16)nx, nyh = (_Float16)ny, nzh = (_Float16)nz;
        const half2v nx2 = {nxh, nxh}, ny2 = {nyh, nyh}, nz2 = {nzh, nzh};

        half2v u2[4], nyc2[4];
        #pragma unroll
        for (int p = 0; p < 4; ++p) {
            u2[p]   = nx2 * st2[p] - nz2 * ct2[p];    // v_pk ops
            nyc2[p] = ny2 * cp2[p];
        }

        f32x4 acc0 = {0.f, 0.f, 0.f, 0.f};            // tiles 0-3
        f32x4 acc1 = {0.f, 0.f, 0.f, 0.f};            // tiles 4-7 (indep chain)
        #pragma unroll
        for (int tl = 0; tl < 8; ++tl) {
            const _Float16 uh = (tl & 1) ? u2[tl >> 1].y : u2[tl >> 1].x;
            const half2v ub = {uh, uh};
            h8u pk;
            #pragma unroll
            for (int p = 0; p < 4; ++p) {
                const half2v d2 = sp2[p] * ub + nyc2[p];   // v_pk_fma_f16 RNE
                pk.h2[p] = d2;
                pk.u[p] &= 0x7FFF7FFFu;                    // packed |.|
            }
            const half8 Hf = lds_hf[tl * 64 + lane];       // ds_read_b128
            if (tl < 4) acc0 = __builtin_amdgcn_mfma_f32_16x16x32_f16(Hf, pk.v, acc0, 0, 0, 0);
            else        acc1 = __builtin_amdgcn_mfma_f32_16x16x32_f16(Hf, pk.v, acc1, 0, 0, 0);
        }

        if (cg == 0) {   // lanes 0-15: rows 0-2 = channels, col = pixel
            const float l0 = acc0[0] + acc1[0] + fmaf(nx, Wl[0], fmaf(ny, Wl[3], nz * Wl[6]));
            const float l1 = acc0[1] + acc1[1] + fmaf(nx, Wl[1], fmaf(ny, Wl[4], nz * Wl[7]));
            const float l2 = acc0[2] + acc1[2] + fmaf(nx, Wl[2], fmaf(ny, Wl[5], nz * Wl[8]));
            lds_light[wave][pxl]       = l0;
            lds_light[wave][64 + pxl]  = l1;
            lds_light[wave][128 + pxl] = l2;
        }
    }
    // lds_light produced & consumed by the SAME wave: LDS is in-order, no barrier
    const size_t bbase = (size_t)b * 3 * HW + wavepx0;
    #pragma unroll
    for (int c = 0; c < 3; ++c) {
        const size_t o = bbase + (size_t)c * HW + lane;
        out[o] = lds_light[wave][c * 64 + lane] * albedo[o];
    }
}

extern "C" void kernel_launch(void* const* d_in, const int* in_sizes, int n_in,
                              void* d_out, int out_size, void* d_ws, size_t ws_size,
                              hipStream_t stream)
{
    const float* env    = (const float*)d_in[0];
    const float* normal = (const float*)d_in[1];
    const float* albedo = (const float*)d_in[2];
    float* out          = (float*)d_out;
    char*  ws           = (char*)d_ws;

    const int B = in_sizes[0] / (16 * 32 * 3);               // = 2

    half8* hf_g = (half8*)ws;                                // B*512*16 B
    float* Wm   = (float*)(ws + (size_t)B * 512 * 16);       // B*9 floats

    setup_kernel<<<dim3(B), 256, 0, stream>>>(env, hf_g, Wm);

    // 256 px per block; grid (1024, B) = 2048 blocks
    dim3 grid(HW / (WAVES * GROUPS * 16), B);
    env_render_main<<<grid, 256, 0, stream>>>(normal, albedo, hf_g, Wm, out);
}